// Round 9
// baseline (693.277 us; speedup 1.0000x reference)
//
#include <hip/hip_runtime.h>
#include <math.h>

#define N_NODES 102400
#define N_EDGES 1638400
#define G_GRAPHS 256
#define F_IN  64
#define H1    4
#define C1    32
#define F_MID 128
#define C2    32
#define CLIN  5
#define NEG   0.2f

__device__ __forceinline__ float lrelu(float x) { return x > 0.f ? x : NEG * x; }
__device__ __forceinline__ float elu(float x)   { return x > 0.f ? x : expm1f(x); }

// round-to-nearest-even fp32 -> bf16 (as ushort)
__device__ __forceinline__ unsigned short f2bf(float f) {
    unsigned u = __float_as_uint(f);
    u = (u + 0x7fffu + ((u >> 16) & 1u)) >> 16;
    return (unsigned short)u;
}
// unpack 4 bf16 (uint2) -> float4
__device__ __forceinline__ float4 bf2f4(uint2 p) {
    return make_float4(__uint_as_float(p.x << 16), __uint_as_float(p.x & 0xffff0000u),
                       __uint_as_float(p.y << 16), __uint_as_float(p.y & 0xffff0000u));
}

// ---------------- CSR build ----------------
__global__ __launch_bounds__(256) void hist_k(const int* __restrict__ ei, int* __restrict__ deg) {
    int i = blockIdx.x * 256 + threadIdx.x;
    if (i < N_EDGES) atomicAdd(&deg[ei[N_EDGES + i]], 1);
}

__global__ __launch_bounds__(256) void scanA(const int* __restrict__ deg,
                                             int* __restrict__ excl, int* __restrict__ bsum) {
    __shared__ int s[256];
    int t = threadIdx.x;
    int n = blockIdx.x * 256 + t;
    int v = deg[n];
    s[t] = v;
    __syncthreads();
    for (int off = 1; off < 256; off <<= 1) {
        int tmp = (t >= off) ? s[t - off] : 0;
        __syncthreads();
        s[t] += tmp;
        __syncthreads();
    }
    excl[n] = s[t] - v;
    if (t == 255) bsum[blockIdx.x] = s[255];
}

__global__ __launch_bounds__(512) void scanB(const int* __restrict__ bsum, int* __restrict__ boff) {
    __shared__ int s[512];
    int t = threadIdx.x;
    int v = (t < 400) ? bsum[t] : 0;
    s[t] = v;
    __syncthreads();
    for (int off = 1; off < 512; off <<= 1) {
        int tmp = (t >= off) ? s[t - off] : 0;
        __syncthreads();
        s[t] += tmp;
        __syncthreads();
    }
    if (t < 400) boff[t] = s[t] - v;
}

__global__ __launch_bounds__(256) void scanC(int* __restrict__ row_ptr, const int* __restrict__ boff,
                                             int* __restrict__ cursor) {
    int n = blockIdx.x * 256 + threadIdx.x;
    int v = row_ptr[n] + boff[blockIdx.x];
    row_ptr[n] = v;
    cursor[n] = v;
}

__global__ __launch_bounds__(256) void scatter_k(const int* __restrict__ ei,
                                                 int* __restrict__ cursor, int* __restrict__ col) {
    int i = blockIdx.x * 256 + threadIdx.x;
    if (i < N_EDGES) {
        int d = ei[N_EDGES + i];
        int pos = atomicAdd(&cursor[d], 1);
        col[pos] = ei[i];
    }
}

// ---- wa[k][o] : o<4 -> W1[:,h,:]@a_src1[h], o>=4 -> @a_dst1[h-4]  (64x8) ----
__global__ __launch_bounds__(512) void wa_k(
    const float* __restrict__ W1, const float* __restrict__ a_src,
    const float* __restrict__ a_dst, float* __restrict__ wa)
{
    int t = threadIdx.x;
    int k = t >> 3, o = t & 7;
    int h = o & 3;
    const float* a = (o < 4) ? a_src : a_dst;
    float s = 0.f;
#pragma unroll
    for (int c = 0; c < C1; ++c) s += W1[k * F_MID + h * C1 + c] * a[h * C1 + c];
    wa[k * 8 + o] = s;
}

// ---- al1 = x @ wa  (fp32 logits), and xh = bf16(x) packed table ----
__global__ __launch_bounds__(256) void al1_k(
    const float* __restrict__ x, const float* __restrict__ wa,
    float* __restrict__ al1, unsigned short* __restrict__ xh)
{
    __shared__ float xs[32][65];
    __shared__ float was[64][8];
    int t = threadIdx.x;
    int n0 = blockIdx.x * 32;
#pragma unroll
    for (int j = 0; j < 8; ++j) {
        int idx = t + 256 * j;
        float v = x[(size_t)n0 * F_IN + idx];
        xs[idx >> 6][idx & 63] = v;
        xh[(size_t)n0 * F_IN + idx] = f2bf(v);
    }
    if (t < 128) ((float4*)was)[t] = ((const float4*)wa)[t];
    __syncthreads();
    int nl = t >> 3, o = t & 7;
    float acc = 0.f;
#pragma unroll
    for (int k = 0; k < F_IN; ++k) acc += xs[nl][k] * was[k][o];
    al1[(size_t)(n0 + nl) * 8 + o] = acc;
}

// ---- fused layer-1: one WAVE per dst; gathers bf16 x rows (128 B). ----
// lane=(h,c): h=lane>>4 head, c=lane&15 -> channels [4c,4c+4) via uint2.
// NO min-wave clamp (R5: forced bound -> 2 GB scratch spill).
__global__ __launch_bounds__(256) void gather1(
    const int* __restrict__ row_ptr, const int* __restrict__ row_end,
    const int* __restrict__ col, const unsigned short* __restrict__ xh,
    const float* __restrict__ al1, const float* __restrict__ W1,
    const float* __restrict__ b1, const float* __restrict__ W2,
    const float* __restrict__ a_src2, const float* __restrict__ a_dst2,
    unsigned short* __restrict__ h2h, float* __restrict__ al_s2, float* __restrict__ al_d2)
{
    __shared__ __align__(16) float agg[4][4][68];   // [dstslot][head][k(+pad)]
    __shared__ float invden[4][4];
    __shared__ __align__(16) float os[4][F_MID];
    __shared__ float hsh[4][C2 + 1];
    int t = threadIdx.x;
    int wv = t >> 6;                 // dst slot (one wave each)
    int lane = t & 63;
    int h = lane >> 4;               // head
    int c = lane & 15;               // uint2 slot: channels [4c,4c+4)
    int d = blockIdx.x * 4 + wv;
    const uint2* x2p = (const uint2*)xh;

    {   // ---------- phase 1: aggregate bf16 x over incoming edges ----------
        float adv = al1[d * 8 + 4 + h];
        float w = __expf(lrelu(al1[d * 8 + h] + adv));       // self loop
        float4 xv = bf2f4(x2p[(size_t)d * 16 + c]);
        float4 acc = make_float4(w * xv.x, w * xv.y, w * xv.z, w * xv.w);
        float den = w;
        int e0 = row_ptr[d], e1 = row_end[d];
        int e = e0;
        for (; e + 4 <= e1; e += 4) {
            int s0 = col[e], s1 = col[e + 1], s2 = col[e + 2], s3 = col[e + 3];
            float av0 = al1[s0 * 8 + h];
            float av1 = al1[s1 * 8 + h];
            float av2 = al1[s2 * 8 + h];
            float av3 = al1[s3 * 8 + h];
            uint2 p0 = x2p[(size_t)s0 * 16 + c];
            uint2 p1 = x2p[(size_t)s1 * 16 + c];
            uint2 p2 = x2p[(size_t)s2 * 16 + c];
            uint2 p3 = x2p[(size_t)s3 * 16 + c];
            float4 x0 = bf2f4(p0);
            float4 x1 = bf2f4(p1);
            float4 x2 = bf2f4(p2);
            float4 x3 = bf2f4(p3);
            float w0 = __expf(lrelu(av0 + adv));
            float w1 = __expf(lrelu(av1 + adv));
            float w2 = __expf(lrelu(av2 + adv));
            float w3 = __expf(lrelu(av3 + adv));
            acc.x += w0 * x0.x + w1 * x1.x + w2 * x2.x + w3 * x3.x;
            acc.y += w0 * x0.y + w1 * x1.y + w2 * x2.y + w3 * x3.y;
            acc.z += w0 * x0.z + w1 * x1.z + w2 * x2.z + w3 * x3.z;
            acc.w += w0 * x0.w + w1 * x1.w + w2 * x2.w + w3 * x3.w;
            den += w0 + w1 + w2 + w3;
        }
        for (; e < e1; ++e) {
            int s = col[e];
            float av = al1[s * 8 + h];
            float4 xs = bf2f4(x2p[(size_t)s * 16 + c]);
            float we = __expf(lrelu(av + adv));
            acc.x += we * xs.x; acc.y += we * xs.y;
            acc.z += we * xs.z; acc.w += we * xs.w;
            den += we;
        }
        *(float4*)&agg[wv][h][4 * c] = acc;
        if (c == 0) invden[wv][h] = 1.f / den;
    }
    __syncthreads();
    {   // ---------- phase 2: os = elu(agg @ W1 * invden + b1)  (512 outs, 2/thread) ----------
        int ch = t & 127;            // out channel
        int r0 = t >> 7;             // dsts r0 and r0+2
        int hh = ch >> 5;
        float A0 = 0.f, A1 = 0.f;
        for (int k = 0; k < F_IN; ++k) {
            float wv1 = W1[k * F_MID + ch];
            A0 += agg[r0][hh][k] * wv1;
            A1 += agg[r0 + 2][hh][k] * wv1;
        }
        float bb = b1[ch];
        os[r0][ch]     = elu(A0 * invden[r0][hh] + bb);
        os[r0 + 2][ch] = elu(A1 * invden[r0 + 2][hh] + bb);
    }
    __syncthreads();
    {   // ---------- phase 3: h2 = os @ W2 (bf16 store), then layer-2 logits ----------
        if (t < 128) {
            int r = t >> 5, ch = t & 31;
            float B = 0.f;
            for (int k = 0; k < F_MID; ++k) B += os[r][k] * W2[k * C2 + ch];
            h2h[(size_t)(blockIdx.x * 4 + r) * C2 + ch] = f2bf(B);
            hsh[r][ch] = B;
        }
        __syncthreads();
        if (t < 8) {
            int r = t & 3, which = t >> 2;
            const float* a = which ? a_dst2 : a_src2;
            float s = 0.f;
#pragma unroll
            for (int k = 0; k < C2; ++k) s += hsh[r][k] * a[k];
            if (which) al_d2[blockIdx.x * 4 + r] = s;
            else       al_s2[blockIdx.x * 4 + r] = s;
        }
    }
}

// ---- layer-2 gather (bf16 rows, 64 B) + normalize + ELU + pooled reduce ----
__global__ __launch_bounds__(256) void gather2(
    const int* __restrict__ row_ptr, const int* __restrict__ row_end,
    const int* __restrict__ col, const float* __restrict__ al_src,
    const float* __restrict__ al_dst, const unsigned short* __restrict__ h2h,
    const float* __restrict__ b2, const int* __restrict__ batch,
    float* __restrict__ pooled)
{
    __shared__ float sv[32][C2];
    int t = threadIdx.x;
    int r = t >> 3;
    int c = t & 7;
    int d = blockIdx.x * 32 + r;
    const uint2* h2v = (const uint2*)h2h;
    float ad = al_dst[d];
    float w = __expf(lrelu(al_src[d] + ad));
    float4 v = bf2f4(h2v[(size_t)d * 8 + c]);
    float ax = w * v.x, ay = w * v.y, az = w * v.z, aw = w * v.w;
    float den = w;
    int e0 = row_ptr[d], e1 = row_end[d];
    int e = e0;
    for (; e + 4 <= e1; e += 4) {
        int s0 = col[e], s1 = col[e + 1], s2 = col[e + 2], s3 = col[e + 3];
        uint2 p0 = h2v[(size_t)s0 * 8 + c];
        uint2 p1 = h2v[(size_t)s1 * 8 + c];
        uint2 p2 = h2v[(size_t)s2 * 8 + c];
        uint2 p3 = h2v[(size_t)s3 * 8 + c];
        float4 v0 = bf2f4(p0);
        float4 v1 = bf2f4(p1);
        float4 v2 = bf2f4(p2);
        float4 v3 = bf2f4(p3);
        float w0 = __expf(lrelu(al_src[s0] + ad));
        float w1 = __expf(lrelu(al_src[s1] + ad));
        float w2 = __expf(lrelu(al_src[s2] + ad));
        float w3 = __expf(lrelu(al_src[s3] + ad));
        ax += w0 * v0.x + w1 * v1.x + w2 * v2.x + w3 * v3.x;
        ay += w0 * v0.y + w1 * v1.y + w2 * v2.y + w3 * v3.y;
        az += w0 * v0.z + w1 * v1.z + w2 * v2.z + w3 * v3.z;
        aw += w0 * v0.w + w1 * v1.w + w2 * v2.w + w3 * v3.w;
        den += w0 + w1 + w2 + w3;
    }
    for (; e < e1; ++e) {
        int s = col[e];
        float4 vs = bf2f4(h2v[(size_t)s * 8 + c]);
        float we = __expf(lrelu(al_src[s] + ad));
        ax += we * vs.x; ay += we * vs.y; az += we * vs.z; aw += we * vs.w;
        den += we;
    }
    float inv = 1.f / den;
    const float4 bv = ((const float4*)b2)[c];
    sv[r][4 * c + 0] = elu(ax * inv + bv.x);
    sv[r][4 * c + 1] = elu(ay * inv + bv.y);
    sv[r][4 * c + 2] = elu(az * inv + bv.z);
    sv[r][4 * c + 3] = elu(aw * inv + bv.w);
    __syncthreads();
    int d0 = blockIdx.x * 32;
    int g0 = batch[d0], g1 = batch[d0 + 31];
    if (t < 64) {
        int which = t >> 5, ch = t & 31;
        int g = which ? g1 : g0;
        if (which == 0 || g1 != g0) {
            float s = 0.f;
            for (int rr = 0; rr < 32; ++rr)
                if (batch[d0 + rr] == g) s += sv[rr][ch];
            atomicAdd(&pooled[g * C2 + ch], s);
        }
    }
}

// ---- classifier head: one thread per graph (400 nodes/graph exactly) ----
__global__ __launch_bounds__(256) void head_k(
    const float* __restrict__ pooled, const float* __restrict__ clinical,
    const float* __restrict__ Wc1, const float* __restrict__ bc1,
    const float* __restrict__ Wc2, const float* __restrict__ bc2,
    float* __restrict__ out)
{
    int g = threadIdx.x;
    float fused[C2 + CLIN];
    const float inv = 1.f / 400.f;
#pragma unroll
    for (int c = 0; c < C2; ++c) fused[c] = pooled[g * C2 + c] * inv;
#pragma unroll
    for (int c = 0; c < CLIN; ++c) fused[C2 + c] = clinical[g * CLIN + c];
    float o = bc2[0];
#pragma unroll
    for (int j = 0; j < 16; ++j) {
        float acc = bc1[j];
#pragma unroll
        for (int k = 0; k < C2 + CLIN; ++k) acc += fused[k] * Wc1[k * 16 + j];
        o += (acc > 0.f ? acc : expm1f(acc)) * Wc2[j];
    }
    out[g] = o;
}

extern "C" void kernel_launch(void* const* d_in, const int* in_sizes, int n_in,
                              void* d_out, int out_size, void* d_ws, size_t ws_size,
                              hipStream_t stream) {
    const float* x        = (const float*)d_in[0];
    const int*   ei       = (const int*)  d_in[1];
    const int*   batch    = (const int*)  d_in[2];
    const float* clinical = (const float*)d_in[3];
    const float* W1       = (const float*)d_in[4];
    const float* a_src1   = (const float*)d_in[5];
    const float* a_dst1   = (const float*)d_in[6];
    const float* b1       = (const float*)d_in[7];
    const float* W2       = (const float*)d_in[8];
    const float* a_src2   = (const float*)d_in[9];
    const float* a_dst2   = (const float*)d_in[10];
    const float* b2       = (const float*)d_in[11];
    const float* Wc1      = (const float*)d_in[12];
    const float* bc1      = (const float*)d_in[13];
    const float* Wc2      = (const float*)d_in[14];
    const float* bc2      = (const float*)d_in[15];
    float* out = (float*)d_out;

    const size_t N = N_NODES;
    float* ws = (float*)d_ws;
    size_t off = 0;
    float* al1    = ws + off; off += N * 8;
    float* al_s2  = ws + off; off += N;
    float* al_d2  = ws + off; off += N;
    float* pooled = ws + off; off += (size_t)G_GRAPHS * C2;
    float* wa     = ws + off; off += 512;
    unsigned short* xh  = (unsigned short*)(ws + off); off += N * F_IN / 2;  // bf16 x
    unsigned short* h2h = (unsigned short*)(ws + off); off += N * C2 / 2;    // bf16 h2
    int* deg     = (int*)(ws + off); off += N;
    int* row_ptr = (int*)(ws + off); off += N;
    int* cursor  = (int*)(ws + off); off += N;        // after scatter: row ends
    int* bsum    = (int*)(ws + off); off += 512;
    int* boff    = (int*)(ws + off); off += 512;
    int* col     = (int*)(ws + off); off += N_EDGES;

    hipMemsetAsync(deg, 0, N * sizeof(int), stream);
    hipMemsetAsync(pooled, 0, G_GRAPHS * C2 * sizeof(float), stream);

    // CSR build
    hist_k   <<<(N_EDGES + 255) / 256, 256, 0, stream>>>(ei, deg);
    scanA    <<<N_NODES / 256, 256, 0, stream>>>(deg, row_ptr, bsum);
    scanB    <<<1, 512, 0, stream>>>(bsum, boff);
    scanC    <<<N_NODES / 256, 256, 0, stream>>>(row_ptr, boff, cursor);
    scatter_k<<<(N_EDGES + 255) / 256, 256, 0, stream>>>(ei, cursor, col);

    // layer-1 attention logits + bf16 x table
    wa_k <<<1, 512, 0, stream>>>(W1, a_src1, a_dst1, wa);
    al1_k<<<N_NODES / 32, 256, 0, stream>>>(x, wa, al1, xh);

    // fused layer 1 (+ layer-2 GEMM & logits), one wave per dst
    gather1<<<N_NODES / 4, 256, 0, stream>>>(row_ptr, cursor, col, xh, al1, W1, b1,
                                             W2, a_src2, a_dst2, h2h, al_s2, al_d2);

    // layer 2 gather (+ fused pooling)
    gather2<<<N_NODES / 32, 256, 0, stream>>>(row_ptr, cursor, col, al_s2, al_d2, h2h,
                                              b2, batch, pooled);

    // head
    head_k<<<1, G_GRAPHS, 0, stream>>>(pooled, clinical, Wc1, bc1, Wc2, bc2, out);
}

// Round 10
// 577.351 us; speedup vs baseline: 1.2008x; 1.2008x over previous
//
#include <hip/hip_runtime.h>
#include <math.h>

#define N_NODES 102400
#define N_EDGES 1638400
#define G_GRAPHS 256
#define F_IN  64
#define H1    4
#define C1    32
#define F_MID 128
#define C2    32
#define CLIN  5
#define NEG   0.2f

__device__ __forceinline__ float lrelu(float x) { return x > 0.f ? x : NEG * x; }
__device__ __forceinline__ float elu(float x)   { return x > 0.f ? x : expm1f(x); }

// round-to-nearest-even fp32 -> bf16 (as ushort)
__device__ __forceinline__ unsigned short f2bf(float f) {
    unsigned u = __float_as_uint(f);
    u = (u + 0x7fffu + ((u >> 16) & 1u)) >> 16;
    return (unsigned short)u;
}
// unpack 4 bf16 (uint2) -> float4
__device__ __forceinline__ float4 bf2f4(uint2 p) {
    return make_float4(__uint_as_float(p.x << 16), __uint_as_float(p.x & 0xffff0000u),
                       __uint_as_float(p.y << 16), __uint_as_float(p.y & 0xffff0000u));
}

// ---------------- CSR build ----------------
__global__ __launch_bounds__(256) void hist_k(const int* __restrict__ ei, int* __restrict__ deg) {
    int i = blockIdx.x * 256 + threadIdx.x;
    if (i < N_EDGES) atomicAdd(&deg[ei[N_EDGES + i]], 1);
}

__global__ __launch_bounds__(256) void scanA(const int* __restrict__ deg,
                                             int* __restrict__ excl, int* __restrict__ bsum) {
    __shared__ int s[256];
    int t = threadIdx.x;
    int n = blockIdx.x * 256 + t;
    int v = deg[n];
    s[t] = v;
    __syncthreads();
    for (int off = 1; off < 256; off <<= 1) {
        int tmp = (t >= off) ? s[t - off] : 0;
        __syncthreads();
        s[t] += tmp;
        __syncthreads();
    }
    excl[n] = s[t] - v;
    if (t == 255) bsum[blockIdx.x] = s[255];
}

__global__ __launch_bounds__(512) void scanB(const int* __restrict__ bsum, int* __restrict__ boff) {
    __shared__ int s[512];
    int t = threadIdx.x;
    int v = (t < 400) ? bsum[t] : 0;
    s[t] = v;
    __syncthreads();
    for (int off = 1; off < 512; off <<= 1) {
        int tmp = (t >= off) ? s[t - off] : 0;
        __syncthreads();
        s[t] += tmp;
        __syncthreads();
    }
    if (t < 400) boff[t] = s[t] - v;
}

__global__ __launch_bounds__(256) void scanC(int* __restrict__ row_ptr, const int* __restrict__ boff,
                                             int* __restrict__ cursor) {
    int n = blockIdx.x * 256 + threadIdx.x;
    int v = row_ptr[n] + boff[blockIdx.x];
    row_ptr[n] = v;
    cursor[n] = v;
}

__global__ __launch_bounds__(256) void scatter_k(const int* __restrict__ ei,
                                                 int* __restrict__ cursor, int* __restrict__ col) {
    int i = blockIdx.x * 256 + threadIdx.x;
    if (i < N_EDGES) {
        int d = ei[N_EDGES + i];
        int pos = atomicAdd(&cursor[d], 1);
        col[pos] = ei[i];
    }
}

// ---- wa[k][o] : o<4 -> W1[:,h,:]@a_src1[h], o>=4 -> @a_dst1[h-4]  (64x8) ----
__global__ __launch_bounds__(512) void wa_k(
    const float* __restrict__ W1, const float* __restrict__ a_src,
    const float* __restrict__ a_dst, float* __restrict__ wa)
{
    int t = threadIdx.x;
    int k = t >> 3, o = t & 7;
    int h = o & 3;
    const float* a = (o < 4) ? a_src : a_dst;
    float s = 0.f;
#pragma unroll
    for (int c = 0; c < C1; ++c) s += W1[k * F_MID + h * C1 + c] * a[h * C1 + c];
    wa[k * 8 + o] = s;
}

// ---- al1 = x @ wa  (fp32 logits), and xh = bf16(x) packed table ----
__global__ __launch_bounds__(256) void al1_k(
    const float* __restrict__ x, const float* __restrict__ wa,
    float* __restrict__ al1, unsigned short* __restrict__ xh)
{
    __shared__ float xs[32][65];
    __shared__ float was[64][8];
    int t = threadIdx.x;
    int n0 = blockIdx.x * 32;
#pragma unroll
    for (int j = 0; j < 8; ++j) {
        int idx = t + 256 * j;
        float v = x[(size_t)n0 * F_IN + idx];
        xs[idx >> 6][idx & 63] = v;
        xh[(size_t)n0 * F_IN + idx] = f2bf(v);
    }
    if (t < 128) ((float4*)was)[t] = ((const float4*)wa)[t];
    __syncthreads();
    int nl = t >> 3, o = t & 7;
    float acc = 0.f;
#pragma unroll
    for (int k = 0; k < F_IN; ++k) acc += xs[nl][k] * was[k][o];
    al1[(size_t)(n0 + nl) * 8 + o] = acc;
}

// ---- fused layer-1: one WAVE per dst; bf16 x rows (128 B); SCALARIZED edge loop:
// d is wave-uniform, so e0/e1/col[e] go to SGPRs via readfirstlane -> gather
// addresses are SGPR-base + loop-invariant lane offset. Target VGPR <= 64.
__global__ __launch_bounds__(256) void gather1(
    const int* __restrict__ row_ptr, const int* __restrict__ row_end,
    const int* __restrict__ col, const unsigned short* __restrict__ xh,
    const float* __restrict__ al1, const float* __restrict__ W1,
    const float* __restrict__ b1, const float* __restrict__ W2,
    const float* __restrict__ a_src2, const float* __restrict__ a_dst2,
    unsigned short* __restrict__ h2h, float* __restrict__ al_s2, float* __restrict__ al_d2)
{
    __shared__ __align__(16) float agg[4][4][68];   // [dstslot][head][k(+pad)]
    __shared__ float invden[4][4];
    __shared__ __align__(16) float os[4][F_MID];
    __shared__ float hsh[4][C2 + 1];
    int t = threadIdx.x;
    int wv = t >> 6;                 // dst slot (one wave each)
    int lane = t & 63;
    int h = lane >> 4;               // head
    int c = lane & 15;               // uint2 slot: channels [4c,4c+4)
    int d = blockIdx.x * 4 + wv;
    const uint2* x2p = (const uint2*)xh;

    {   // ---------- phase 1: aggregate bf16 x over incoming edges ----------
        float adv = al1[d * 8 + 4 + h];
        float w = __expf(lrelu(al1[d * 8 + h] + adv));       // self loop
        float4 xv = bf2f4(x2p[(size_t)d * 16 + c]);
        float4 acc = make_float4(w * xv.x, w * xv.y, w * xv.z, w * xv.w);
        float den = w;
        int e0 = __builtin_amdgcn_readfirstlane(row_ptr[d]);
        int e1 = __builtin_amdgcn_readfirstlane(row_end[d]);
        int e = e0;
        for (; e + 4 <= e1; e += 4) {
            int s0 = __builtin_amdgcn_readfirstlane(col[e]);
            int s1 = __builtin_amdgcn_readfirstlane(col[e + 1]);
            int s2 = __builtin_amdgcn_readfirstlane(col[e + 2]);
            int s3 = __builtin_amdgcn_readfirstlane(col[e + 3]);
            const uint2*  r0 = x2p + (size_t)s0 * 16;
            const uint2*  r1 = x2p + (size_t)s1 * 16;
            const uint2*  r2 = x2p + (size_t)s2 * 16;
            const uint2*  r3 = x2p + (size_t)s3 * 16;
            const float*  a0 = al1 + s0 * 8;
            const float*  a1 = al1 + s1 * 8;
            const float*  a2 = al1 + s2 * 8;
            const float*  a3 = al1 + s3 * 8;
            uint2 p0 = r0[c];
            uint2 p1 = r1[c];
            uint2 p2 = r2[c];
            uint2 p3 = r3[c];
            float av0 = a0[h];
            float av1 = a1[h];
            float av2 = a2[h];
            float av3 = a3[h];
            float w0 = __expf(lrelu(av0 + adv));
            float w1 = __expf(lrelu(av1 + adv));
            float w2 = __expf(lrelu(av2 + adv));
            float w3 = __expf(lrelu(av3 + adv));
            float4 x0 = bf2f4(p0);
            float4 x1 = bf2f4(p1);
            float4 x2 = bf2f4(p2);
            float4 x3 = bf2f4(p3);
            acc.x += w0 * x0.x + w1 * x1.x + w2 * x2.x + w3 * x3.x;
            acc.y += w0 * x0.y + w1 * x1.y + w2 * x2.y + w3 * x3.y;
            acc.z += w0 * x0.z + w1 * x1.z + w2 * x2.z + w3 * x3.z;
            acc.w += w0 * x0.w + w1 * x1.w + w2 * x2.w + w3 * x3.w;
            den += w0 + w1 + w2 + w3;
        }
        for (; e < e1; ++e) {
            int s = __builtin_amdgcn_readfirstlane(col[e]);
            float av = al1[s * 8 + h];
            float4 xs = bf2f4(x2p[(size_t)s * 16 + c]);
            float we = __expf(lrelu(av + adv));
            acc.x += we * xs.x; acc.y += we * xs.y;
            acc.z += we * xs.z; acc.w += we * xs.w;
            den += we;
        }
        *(float4*)&agg[wv][h][4 * c] = acc;
        if (c == 0) invden[wv][h] = 1.f / den;
    }
    __syncthreads();
    {   // ---------- phase 2: os = elu(agg @ W1 * invden + b1)  (512 outs, 2/thread) ----------
        int ch = t & 127;            // out channel
        int r0 = t >> 7;             // dsts r0 and r0+2
        int hh = ch >> 5;
        float A0 = 0.f, A1 = 0.f;
#pragma unroll 4
        for (int k = 0; k < F_IN; ++k) {
            float wv1 = W1[k * F_MID + ch];
            A0 += agg[r0][hh][k] * wv1;
            A1 += agg[r0 + 2][hh][k] * wv1;
        }
        float bb = b1[ch];
        os[r0][ch]     = elu(A0 * invden[r0][hh] + bb);
        os[r0 + 2][ch] = elu(A1 * invden[r0 + 2][hh] + bb);
    }
    __syncthreads();
    {   // ---------- phase 3: h2 = os @ W2 (bf16 store), then layer-2 logits ----------
        if (t < 128) {
            int r = t >> 5, ch = t & 31;
            float B = 0.f;
#pragma unroll 4
            for (int k = 0; k < F_MID; ++k) B += os[r][k] * W2[k * C2 + ch];
            h2h[(size_t)(blockIdx.x * 4 + r) * C2 + ch] = f2bf(B);
            hsh[r][ch] = B;
        }
        __syncthreads();
        if (t < 8) {
            int r = t & 3, which = t >> 2;
            const float* a = which ? a_dst2 : a_src2;
            float s = 0.f;
#pragma unroll
            for (int k = 0; k < C2; ++k) s += hsh[r][k] * a[k];
            if (which) al_d2[blockIdx.x * 4 + r] = s;
            else       al_s2[blockIdx.x * 4 + r] = s;
        }
    }
}

// ---- layer-2 gather (bf16 rows, 64 B) + normalize + ELU + pooled reduce ----
__global__ __launch_bounds__(256) void gather2(
    const int* __restrict__ row_ptr, const int* __restrict__ row_end,
    const int* __restrict__ col, const float* __restrict__ al_src,
    const float* __restrict__ al_dst, const unsigned short* __restrict__ h2h,
    const float* __restrict__ b2, const int* __restrict__ batch,
    float* __restrict__ pooled)
{
    __shared__ float sv[32][C2];
    int t = threadIdx.x;
    int r = t >> 3;
    int c = t & 7;
    int d = blockIdx.x * 32 + r;
    const uint2* h2v = (const uint2*)h2h;
    float ad = al_dst[d];
    float w = __expf(lrelu(al_src[d] + ad));
    float4 v = bf2f4(h2v[(size_t)d * 8 + c]);
    float ax = w * v.x, ay = w * v.y, az = w * v.z, aw = w * v.w;
    float den = w;
    int e0 = row_ptr[d], e1 = row_end[d];
    int e = e0;
    for (; e + 4 <= e1; e += 4) {
        int s0 = col[e], s1 = col[e + 1], s2 = col[e + 2], s3 = col[e + 3];
        uint2 p0 = h2v[(size_t)s0 * 8 + c];
        uint2 p1 = h2v[(size_t)s1 * 8 + c];
        uint2 p2 = h2v[(size_t)s2 * 8 + c];
        uint2 p3 = h2v[(size_t)s3 * 8 + c];
        float4 v0 = bf2f4(p0);
        float4 v1 = bf2f4(p1);
        float4 v2 = bf2f4(p2);
        float4 v3 = bf2f4(p3);
        float w0 = __expf(lrelu(al_src[s0] + ad));
        float w1 = __expf(lrelu(al_src[s1] + ad));
        float w2 = __expf(lrelu(al_src[s2] + ad));
        float w3 = __expf(lrelu(al_src[s3] + ad));
        ax += w0 * v0.x + w1 * v1.x + w2 * v2.x + w3 * v3.x;
        ay += w0 * v0.y + w1 * v1.y + w2 * v2.y + w3 * v3.y;
        az += w0 * v0.z + w1 * v1.z + w2 * v2.z + w3 * v3.z;
        aw += w0 * v0.w + w1 * v1.w + w2 * v2.w + w3 * v3.w;
        den += w0 + w1 + w2 + w3;
    }
    for (; e < e1; ++e) {
        int s = col[e];
        float4 vs = bf2f4(h2v[(size_t)s * 8 + c]);
        float we = __expf(lrelu(al_src[s] + ad));
        ax += we * vs.x; ay += we * vs.y; az += we * vs.z; aw += we * vs.w;
        den += we;
    }
    float inv = 1.f / den;
    const float4 bv = ((const float4*)b2)[c];
    sv[r][4 * c + 0] = elu(ax * inv + bv.x);
    sv[r][4 * c + 1] = elu(ay * inv + bv.y);
    sv[r][4 * c + 2] = elu(az * inv + bv.z);
    sv[r][4 * c + 3] = elu(aw * inv + bv.w);
    __syncthreads();
    int d0 = blockIdx.x * 32;
    int g0 = batch[d0], g1 = batch[d0 + 31];
    if (t < 64) {
        int which = t >> 5, ch = t & 31;
        int g = which ? g1 : g0;
        if (which == 0 || g1 != g0) {
            float s = 0.f;
            for (int rr = 0; rr < 32; ++rr)
                if (batch[d0 + rr] == g) s += sv[rr][ch];
            atomicAdd(&pooled[g * C2 + ch], s);
        }
    }
}

// ---- classifier head: one thread per graph (400 nodes/graph exactly) ----
__global__ __launch_bounds__(256) void head_k(
    const float* __restrict__ pooled, const float* __restrict__ clinical,
    const float* __restrict__ Wc1, const float* __restrict__ bc1,
    const float* __restrict__ Wc2, const float* __restrict__ bc2,
    float* __restrict__ out)
{
    int g = threadIdx.x;
    float fused[C2 + CLIN];
    const float inv = 1.f / 400.f;
#pragma unroll
    for (int c = 0; c < C2; ++c) fused[c] = pooled[g * C2 + c] * inv;
#pragma unroll
    for (int c = 0; c < CLIN; ++c) fused[C2 + c] = clinical[g * CLIN + c];
    float o = bc2[0];
#pragma unroll
    for (int j = 0; j < 16; ++j) {
        float acc = bc1[j];
#pragma unroll
        for (int k = 0; k < C2 + CLIN; ++k) acc += fused[k] * Wc1[k * 16 + j];
        o += (acc > 0.f ? acc : expm1f(acc)) * Wc2[j];
    }
    out[g] = o;
}

extern "C" void kernel_launch(void* const* d_in, const int* in_sizes, int n_in,
                              void* d_out, int out_size, void* d_ws, size_t ws_size,
                              hipStream_t stream) {
    const float* x        = (const float*)d_in[0];
    const int*   ei       = (const int*)  d_in[1];
    const int*   batch    = (const int*)  d_in[2];
    const float* clinical = (const float*)d_in[3];
    const float* W1       = (const float*)d_in[4];
    const float* a_src1   = (const float*)d_in[5];
    const float* a_dst1   = (const float*)d_in[6];
    const float* b1       = (const float*)d_in[7];
    const float* W2       = (const float*)d_in[8];
    const float* a_src2   = (const float*)d_in[9];
    const float* a_dst2   = (const float*)d_in[10];
    const float* b2       = (const float*)d_in[11];
    const float* Wc1      = (const float*)d_in[12];
    const float* bc1      = (const float*)d_in[13];
    const float* Wc2      = (const float*)d_in[14];
    const float* bc2      = (const float*)d_in[15];
    float* out = (float*)d_out;

    const size_t N = N_NODES;
    float* ws = (float*)d_ws;
    size_t off = 0;
    float* al1    = ws + off; off += N * 8;
    float* al_s2  = ws + off; off += N;
    float* al_d2  = ws + off; off += N;
    float* pooled = ws + off; off += (size_t)G_GRAPHS * C2;
    float* wa     = ws + off; off += 512;
    unsigned short* xh  = (unsigned short*)(ws + off); off += N * F_IN / 2;  // bf16 x
    unsigned short* h2h = (unsigned short*)(ws + off); off += N * C2 / 2;    // bf16 h2
    int* deg     = (int*)(ws + off); off += N;
    int* row_ptr = (int*)(ws + off); off += N;
    int* cursor  = (int*)(ws + off); off += N;        // after scatter: row ends
    int* bsum    = (int*)(ws + off); off += 512;
    int* boff    = (int*)(ws + off); off += 512;
    int* col     = (int*)(ws + off); off += N_EDGES;

    hipMemsetAsync(deg, 0, N * sizeof(int), stream);
    hipMemsetAsync(pooled, 0, G_GRAPHS * C2 * sizeof(float), stream);

    // CSR build
    hist_k   <<<(N_EDGES + 255) / 256, 256, 0, stream>>>(ei, deg);
    scanA    <<<N_NODES / 256, 256, 0, stream>>>(deg, row_ptr, bsum);
    scanB    <<<1, 512, 0, stream>>>(bsum, boff);
    scanC    <<<N_NODES / 256, 256, 0, stream>>>(row_ptr, boff, cursor);
    scatter_k<<<(N_EDGES + 255) / 256, 256, 0, stream>>>(ei, cursor, col);

    // layer-1 attention logits + bf16 x table
    wa_k <<<1, 512, 0, stream>>>(W1, a_src1, a_dst1, wa);
    al1_k<<<N_NODES / 32, 256, 0, stream>>>(x, wa, al1, xh);

    // fused layer 1 (+ layer-2 GEMM & logits), one wave per dst, scalarized loop
    gather1<<<N_NODES / 4, 256, 0, stream>>>(row_ptr, cursor, col, xh, al1, W1, b1,
                                             W2, a_src2, a_dst2, h2h, al_s2, al_d2);

    // layer 2 gather (+ fused pooling)
    gather2<<<N_NODES / 32, 256, 0, stream>>>(row_ptr, cursor, col, al_s2, al_d2, h2h,
                                              b2, batch, pooled);

    // head
    head_k<<<1, G_GRAPHS, 0, stream>>>(pooled, clinical, Wc1, bc1, Wc2, bc2, out);
}